// Round 4
// baseline (1897.820 us; speedup 1.0000x reference)
//
#include <hip/hip_runtime.h>

#define NN 50000
#define NN2 50176            // NN padded to 256 multiple (stacked layer-1 GEMM)
#define NE 800000
#define NG 128
#define DIN 1280
#define HIDDEN 256
#define BNS 0.9999950000374997f
#define ATT_SCALE 0.027950849718747373f
#define LN_EPS 1e-5f

typedef __attribute__((ext_vector_type(8))) short short8;
typedef __attribute__((ext_vector_type(4))) float floatx4;

__device__ __forceinline__ float b2f(unsigned short u) {
  return __uint_as_float(((unsigned int)u) << 16);
}
__device__ __forceinline__ unsigned short f2b(float f) {
  unsigned int x = __float_as_uint(f);
  x += 0x7fffu + ((x >> 16) & 1u);
  return (unsigned short)(x >> 16);
}

// ---------------- consolidated weight prep ----------------
struct PrepJob { const float* s; unsigned short* d; int K; int Nc; int special; };
struct PrepJobs { PrepJob j[9]; };

__global__ void prep_k(PrepJobs P) {
  PrepJob pj = P.j[blockIdx.y];
  int idx = blockIdx.x * 256 + threadIdx.x;
  if (idx >= pj.K * pj.Nc) return;
  if (!pj.special) {
    int n = idx / pj.K, k = idx % pj.K;
    pj.d[idx] = f2b(pj.s[(size_t)k * pj.Nc + n]);
  } else {
    // vw [4][256][256] -> d[r][dd] = vw[h][dd][e2], r = h*256+e2
    int r = idx >> 8, dd = idx & 255;
    int hh = r >> 8, e2 = r & 255;
    pj.d[idx] = f2b(pj.s[((size_t)hh * 256 + dd) * 256 + e2]);
  }
}

// M_h = qw_h @ kw_h^T; dst rows [0,1024)
__global__ void mw_k(const float* __restrict__ qw, const float* __restrict__ kw,
                     unsigned short* __restrict__ dst) {
  int col = blockIdx.x;
  int d = threadIdx.x;
  int hh = col >> 8, dp = col & 255;
  const float* qr = qw + ((size_t)hh * 256 + d) * 256;
  const float* kr = kw + ((size_t)hh * 256 + dp) * 256;
  float s = 0.f;
  for (int e = 0; e < 256; e += 4) {
    float4 a = *(const float4*)(qr + e);
    float4 b = *(const float4*)(kr + e);
    s += a.x * b.x + a.y * b.y + a.z * b.z + a.w * b.w;
  }
  dst[(size_t)col * 256 + d] = f2b(s);
}

// ---------------- fused h->bf16 conversion + per-graph sum ----------------
__global__ void cvt_avg_k(const float* __restrict__ h, const int* __restrict__ gid,
                          unsigned short* __restrict__ h_bf, float* __restrict__ out1) {
  int row0 = blockIdx.x * 50;
  int tid = threadIdx.x;
  float acc[5] = {0, 0, 0, 0, 0};
  int cur_g = gid[row0];
  for (int r = 0; r < 50; ++r) {
    int row = row0 + r;
    int g = gid[row];
    if (g != cur_g) {
#pragma unroll
      for (int j = 0; j < 5; ++j) {
        atomicAdd(&out1[(size_t)cur_g * DIN + j * 256 + tid], acc[j]);
        acc[j] = 0.f;
      }
      cur_g = g;
    }
#pragma unroll
    for (int j = 0; j < 5; ++j) {
      float v = h[(size_t)row * DIN + j * 256 + tid];
      acc[j] += v;
      h_bf[(size_t)row * DIN + j * 256 + tid] = f2b(v);
    }
  }
#pragma unroll
  for (int j = 0; j < 5; ++j)
    atomicAdd(&out1[(size_t)cur_g * DIN + j * 256 + tid], acc[j]);
}

__global__ void div_avg_k(const int* __restrict__ start, float* __restrict__ out1) {
  int idx = blockIdx.x * 256 + threadIdx.x;
  if (idx >= NG * DIN) return;
  int g = idx / DIN;
  float cnt = (float)(start[g + 1] - start[g]);
  if (cnt < 1.f) cnt = 1.f;
  out1[idx] /= cnt;
}

// ---------------- graph structure ----------------
__global__ void graph_bounds_k(const int* __restrict__ gid, int* __restrict__ start, int n) {
  int i = blockIdx.x * 256 + threadIdx.x;
  if (i >= n) return;
  int g = gid[i];
  if (i == 0) {
    for (int gg = 0; gg <= g; ++gg) start[gg] = 0;
  } else {
    int gp = gid[i - 1];
    for (int gg = gp + 1; gg <= g; ++gg) start[gg] = i;
  }
  if (i == n - 1) {
    for (int gg = g + 1; gg <= NG; ++gg) start[gg] = n;
  }
}

__global__ void degrees_k(const int* __restrict__ src, const int* __restrict__ dst,
                          int* __restrict__ deg_out, int* __restrict__ deg_in, int e) {
  int i = blockIdx.x * 256 + threadIdx.x;
  if (i >= e) return;
  atomicAdd(&deg_out[src[i]], 1);
  atomicAdd(&deg_in[dst[i]], 1);
}

__global__ void invsqrt_k(const int* __restrict__ deg_out, const int* __restrict__ deg_in,
                          float* __restrict__ ns, float* __restrict__ nd, int n) {
  int i = blockIdx.x * 256 + threadIdx.x;
  if (i >= n) return;
  int a = deg_out[i]; if (a < 1) a = 1;
  int b = deg_in[i];  if (b < 1) b = 1;
  ns[i] = rsqrtf((float)a);
  nd[i] = rsqrtf((float)b);
}

__global__ void scan_local_k(const int* __restrict__ deg, int* __restrict__ row_ptr,
                             int* __restrict__ bsum) {
  __shared__ int buf[256];
  int b = blockIdx.x, t = threadIdx.x;
  int i = b * 256 + t;
  int v = (i < NN) ? deg[i] : 0;
  buf[t] = v;
  __syncthreads();
  for (int off = 1; off < 256; off <<= 1) {
    int tv = (t >= off) ? buf[t - off] : 0;
    __syncthreads();
    buf[t] += tv;
    __syncthreads();
  }
  if (i < NN) row_ptr[i] = buf[t] - v;
  if (t == 255) bsum[b] = buf[255];
}

__global__ void scan_bsum_k(int* __restrict__ bsum, int* __restrict__ boff, int nb,
                            int* __restrict__ row_ptr) {
  __shared__ int buf[256];
  int t = threadIdx.x;
  int v = (t < nb) ? bsum[t] : 0;
  buf[t] = v;
  __syncthreads();
  for (int off = 1; off < 256; off <<= 1) {
    int tv = (t >= off) ? buf[t - off] : 0;
    __syncthreads();
    buf[t] += tv;
    __syncthreads();
  }
  if (t < nb) boff[t] = buf[t] - v;
  if (t == 0) row_ptr[NN] = NE;
}

__global__ void scan_add_k(int* __restrict__ row_ptr, const int* __restrict__ boff) {
  int i = blockIdx.x * 256 + threadIdx.x;
  if (i >= NN) return;
  row_ptr[i] += boff[blockIdx.x];
}

__global__ void fill_csr_k(const int* __restrict__ src, const int* __restrict__ dst,
                           const int* __restrict__ row_ptr, int* __restrict__ fill,
                           int* __restrict__ csr_src, int e) {
  int i = blockIdx.x * 256 + threadIdx.x;
  if (i >= e) return;
  int d = dst[i];
  int pos = row_ptr[d] + atomicAdd(&fill[d], 1);
  csr_src[pos] = src[i];
}

// ---------------- bf16 MFMA GEMM, 256x128 tile, BK=64 ----------------
// C[M,Nc] = A[M,K] * Bt[Nc,K]
// MODE 0: bf16 out
// MODE 2: +bias relu bf16 out
// MODE 3: gate epilogue: sigmoid(acc+bias)*xcat[:,c] + (1-..)*xcat[:,256+c] -> bf16
// MODE 4: n0<1024 -> att epilogue (atomicAdd, no store); else bf16 store ld=1024
// MODE 5: A scaled by ascale[row*4+(k0>>8)] at staging; bf16 out
// MODE 6: bf16 out + elr for cols >= esplit (al/ar dots, heads of 64 cols)
// MODE 7: stacked layer-1: B = (m0<esplit ? Bt : Bt2); bf16 out; elr for rows >= esplit
template <int MODE>
__global__ __launch_bounds__(256, 2) void gemm_bf16(
    const unsigned short* __restrict__ A,
    const unsigned short* __restrict__ Bt,
    const unsigned short* __restrict__ Bt2,
    void* __restrict__ Cout,
    const float* __restrict__ bias,
    int M, int K, int Nc,
    const unsigned short* __restrict__ xaux,
    float* __restrict__ faux,
    const float* __restrict__ ascale,
    const float* __restrict__ al, const float* __restrict__ ar,
    int esplit) {
  constexpr int SBN = (MODE == 4) ? 32768 : 24576;
  __shared__ unsigned short sbuf[SBN];
  unsigned short* lA = sbuf;           // 256 rows x 64 k = 16384 shorts (32 KB)
  unsigned short* lB = sbuf + 16384;   // 128 rows x 64 k =  8192 shorts (16 KB)
  const int tid = threadIdx.x;
  const int n0 = blockIdx.x * 128;
  const int m0 = blockIdx.y * 256;
  const int w = tid >> 6;
  const int lane = tid & 63;
  const int quad = lane >> 4;
  const int l15 = lane & 15;
  const int js = tid & 7;
  const int mbase = tid >> 3;
  const int wrow = w * 64;

  const unsigned short* Buse = Bt;
  if (MODE == 7 && m0 >= esplit) Buse = Bt2;

  floatx4 acc[4][8];
#pragma unroll
  for (int i = 0; i < 4; ++i)
#pragma unroll
    for (int j = 0; j < 8; ++j) acc[i][j] = (floatx4)0.0f;

  for (int k0 = 0; k0 < K; k0 += 64) {
    __syncthreads();
#pragma unroll
    for (int it = 0; it < 8; ++it) {
      int m = it * 32 + mbase;
      int gm = m0 + m;
      if (gm >= M) gm = M - 1;
      uint4 va = *(const uint4*)(A + (size_t)gm * K + k0 + js * 8);
      if (MODE == 5) {
        float s = ascale[(size_t)gm * 4 + (k0 >> 8)];
        unsigned short* pp = (unsigned short*)&va;
#pragma unroll
        for (int c = 0; c < 8; ++c) pp[c] = f2b(b2f(pp[c]) * s);
      }
      *(uint4*)(lA + (js * 256 + (m ^ js)) * 8) = va;
    }
#pragma unroll
    for (int it = 0; it < 4; ++it) {
      int n = it * 32 + mbase;
      uint4 vb = *(const uint4*)(Buse + (size_t)(n0 + n) * K + k0 + js * 8);
      *(uint4*)(lB + (js * 128 + (n ^ js)) * 8) = vb;
    }
    __syncthreads();
#pragma unroll
    for (int ks = 0; ks < 2; ++ks) {
      int kb = ks * 4 + quad;
      short8 af[4], bfr[8];
#pragma unroll
      for (int ri = 0; ri < 4; ++ri) {
        int r = wrow + ri * 16 + l15;
        af[ri] = *(const short8*)(lA + (kb * 256 + (r ^ kb)) * 8);
      }
#pragma unroll
      for (int ci = 0; ci < 8; ++ci) {
        int c = ci * 16 + l15;
        bfr[ci] = *(const short8*)(lB + (kb * 128 + (c ^ kb)) * 8);
      }
#pragma unroll
      for (int ri = 0; ri < 4; ++ri)
#pragma unroll
        for (int ci = 0; ci < 8; ++ci)
          acc[ri][ci] = __builtin_amdgcn_mfma_f32_16x16x32_bf16(af[ri], bfr[ci], acc[ri][ci], 0, 0, 0);
    }
  }

  if (MODE == 4 && n0 < 1024) {
    // att[n,h] += sum over this block's 128 cols of acc * xb
    __syncthreads();
    int cb = n0 & 255;
#pragma unroll
    for (int it2 = 0; it2 < 16; ++it2) {
      int linear = it2 * 256 + tid;
      int rr = linear >> 4;
      int c8 = (linear & 15) * 8;
      int gr = m0 + rr;
      if (gr >= M) gr = M - 1;
      *(uint4*)(sbuf + rr * 128 + c8) = *(const uint4*)(xaux + (size_t)gr * 256 + cb + c8);
    }
    __syncthreads();
    int head = n0 >> 8;
#pragma unroll
    for (int ri = 0; ri < 4; ++ri) {
      int lrow = wrow + ri * 16 + quad * 4;
#pragma unroll
      for (int r = 0; r < 4; ++r) {
        float p = 0.f;
#pragma unroll
        for (int ci = 0; ci < 8; ++ci)
          p += acc[ri][ci][r] * b2f(sbuf[(lrow + r) * 128 + ci * 16 + l15]);
        p += __shfl_xor(p, 1);
        p += __shfl_xor(p, 2);
        p += __shfl_xor(p, 4);
        p += __shfl_xor(p, 8);
        if (l15 == 0) {
          int grow = m0 + lrow + r;
          if (grow < M) atomicAdd(&faux[(size_t)grow * 4 + head], p * ATT_SCALE);
        }
      }
    }
    return;
  }

#pragma unroll
  for (int ri = 0; ri < 4; ++ri) {
    int row = m0 + wrow + ri * 16 + quad * 4;
#pragma unroll
    for (int ci = 0; ci < 8; ++ci) {
      int col = n0 + ci * 16 + l15;
      float bv = (MODE == 2 || MODE == 3) ? bias[col] : 0.f;
#pragma unroll
      for (int r = 0; r < 4; ++r) {
        if (row + r < M) {
          float v = acc[ri][ci][r];
          if (MODE == 2) {
            v += bv; v = fmaxf(v, 0.f);
            ((unsigned short*)Cout)[(size_t)(row + r) * Nc + col] = f2b(v);
          } else if (MODE == 3) {
            float g = 1.f / (1.f + expf(-(v + bv)));
            float hg = b2f(xaux[(size_t)(row + r) * 512 + col]);
            float ha = b2f(xaux[(size_t)(row + r) * 512 + 256 + col]);
            ((unsigned short*)Cout)[(size_t)(row + r) * 256 + col] = f2b(g * hg + (1.f - g) * ha);
          } else if (MODE == 4) {
            ((unsigned short*)Cout)[(size_t)(row + r) * 1024 + col - 1024] = f2b(v);
          } else {
            ((unsigned short*)Cout)[(size_t)(row + r) * Nc + col] = f2b(v);
          }
        }
      }
    }
  }

  if ((MODE == 6 && n0 >= esplit) || (MODE == 7 && m0 >= esplit)) {
    int hbase = (MODE == 6) ? ((n0 - esplit) >> 6) : (n0 >> 6);
#pragma unroll
    for (int ri = 0; ri < 4; ++ri) {
#pragma unroll
      for (int r = 0; r < 4; ++r) {
        int grow = m0 + wrow + ri * 16 + quad * 4 + r;
        float pl0 = 0, pr0 = 0, pl1 = 0, pr1 = 0;
#pragma unroll
        for (int ci = 0; ci < 4; ++ci) {
          float a0_ = acc[ri][ci][r];
          float a1_ = acc[ri][ci + 4][r];
          float w0l = al[hbase * 64 + ci * 16 + l15];
          float w0r = ar[hbase * 64 + ci * 16 + l15];
          float w1l = al[(hbase + 1) * 64 + ci * 16 + l15];
          float w1r = ar[(hbase + 1) * 64 + ci * 16 + l15];
          pl0 += a0_ * w0l; pr0 += a0_ * w0r;
          pl1 += a1_ * w1l; pr1 += a1_ * w1r;
        }
#pragma unroll
        for (int off = 1; off < 16; off <<= 1) {
          pl0 += __shfl_xor(pl0, off); pr0 += __shfl_xor(pr0, off);
          pl1 += __shfl_xor(pl1, off); pr1 += __shfl_xor(pr1, off);
        }
        if (l15 == 0) {
          int erow = (MODE == 7) ? (grow - esplit) : grow;
          if (erow >= 0 && erow < NN) {
            faux[(size_t)erow * 8 + hbase] = pl0;
            faux[(size_t)erow * 8 + 4 + hbase] = pr0;
            faux[(size_t)erow * 8 + hbase + 1] = pl1;
            faux[(size_t)erow * 8 + 5 + hbase] = pr1;
          }
        }
      }
    }
  }
}

// ---------------- GCN aggregation ----------------
__global__ void gcn_agg_k(const unsigned short* __restrict__ m, int ldm,
                          const int* __restrict__ row_ptr, const int* __restrict__ csr_src,
                          const float* __restrict__ ns, const float* __restrict__ nd,
                          const float* __restrict__ bias,
                          const float* __restrict__ bng, const float* __restrict__ bnb,
                          const unsigned short* __restrict__ resid, int ldr,
                          unsigned short* __restrict__ out, int ldo) {
  int node = blockIdx.x * 4 + (threadIdx.x >> 6);
  if (node >= NN) return;
  int lane = threadIdx.x & 63;
  int s = row_ptr[node], e = row_ptr[node + 1];
  float a0 = 0, a1 = 0, a2 = 0, a3 = 0;
  for (int i = s; i < e; ++i) {
    int u = csr_src[i];
    float w = ns[u];
    ushort4 v = *(const ushort4*)(m + (size_t)u * ldm + lane * 4);
    a0 += w * b2f(v.x); a1 += w * b2f(v.y); a2 += w * b2f(v.z); a3 += w * b2f(v.w);
  }
  float ndv = nd[node];
  int col = lane * 4;
  float vals[4] = {a0, a1, a2, a3};
  ushort4 o;
#pragma unroll
  for (int c = 0; c < 4; ++c) {
    float v = vals[c] * ndv + bias[col + c];
    v = bng[col + c] * v * BNS + bnb[col + c];
    v = fmaxf(v, 0.f);
    if (resid) v += b2f(resid[(size_t)node * ldr + col + c]);
    ((unsigned short*)&o)[c] = f2b(v);
  }
  *(ushort4*)(out + (size_t)node * ldo + col) = o;
}

// ---------------- GAT aggregation (2-pass, no max-shift) ----------------
__global__ void gat_agg_k(const unsigned short* __restrict__ f, int ldf,
                          const int* __restrict__ row_ptr, const int* __restrict__ csr_src,
                          const float* __restrict__ elr,
                          const float* __restrict__ bias,
                          const float* __restrict__ bng, const float* __restrict__ bnb,
                          const unsigned short* __restrict__ resid, int ldr,
                          unsigned short* __restrict__ out, int ldo) {
  int node = blockIdx.x * 4 + (threadIdx.x >> 6);
  if (node >= NN) return;
  int lane = threadIdx.x & 63;
  int s = row_ptr[node], e = row_ptr[node + 1];
  float4 er = *(const float4*)(elr + (size_t)node * 8 + 4);
  float s0 = 0, s1 = 0, s2 = 0, s3 = 0;
  for (int i = s + lane; i < e; i += 64) {
    int u = csr_src[i];
    float4 el = *(const float4*)(elr + (size_t)u * 8);
    float t;
    t = el.x + er.x; t = t > 0.f ? t : 0.2f * t; s0 += expf(t);
    t = el.y + er.y; t = t > 0.f ? t : 0.2f * t; s1 += expf(t);
    t = el.z + er.z; t = t > 0.f ? t : 0.2f * t; s2 += expf(t);
    t = el.w + er.w; t = t > 0.f ? t : 0.2f * t; s3 += expf(t);
  }
#pragma unroll
  for (int off = 1; off < 64; off <<= 1) {
    s0 += __shfl_xor(s0, off);
    s1 += __shfl_xor(s1, off);
    s2 += __shfl_xor(s2, off);
    s3 += __shfl_xor(s3, off);
  }
  int head = lane >> 4;
  float erh = head == 0 ? er.x : head == 1 ? er.y : head == 2 ? er.z : er.w;
  float sh = head == 0 ? s0 : head == 1 ? s1 : head == 2 ? s2 : s3;
  float inv_sh = (sh > 0.f) ? 1.f / sh : 0.f;
  float a0 = 0, a1 = 0, a2 = 0, a3 = 0;
  for (int i = s; i < e; ++i) {
    int u = csr_src[i];
    float t = elr[(size_t)u * 8 + head] + erh;
    t = t > 0.f ? t : 0.2f * t;
    float wgt = expf(t) * inv_sh;
    ushort4 v = *(const ushort4*)(f + (size_t)u * ldf + lane * 4);
    a0 += wgt * b2f(v.x); a1 += wgt * b2f(v.y); a2 += wgt * b2f(v.z); a3 += wgt * b2f(v.w);
  }
  int col = lane * 4;
  float vals[4] = {a0, a1, a2, a3};
  ushort4 o;
#pragma unroll
  for (int c = 0; c < 4; ++c) {
    float v = vals[c] + bias[col + c];
    v = bng[col + c] * v * BNS + bnb[col + c];
    v = (v > 0.f) ? v : (expf(v) - 1.f);
    if (resid) v += b2f(resid[(size_t)node * ldr + col + c]);
    ((unsigned short*)&o)[c] = f2b(v);
  }
  *(ushort4*)(out + (size_t)node * ldo + col) = o;
}

// ---------------- per-graph node softmax ----------------
__global__ void gsoftmax_k(const float* __restrict__ att, const int* __restrict__ start,
                           float* __restrict__ alpha) {
  int g = blockIdx.x;
  int s = start[g], e = start[g + 1];
  int tid = threadIdx.x;
  __shared__ float red[256];
  __shared__ float mh[4], sh[4];
  float lm[4] = {-1e30f, -1e30f, -1e30f, -1e30f};
  for (int i = s + tid; i < e; i += 256) {
    float4 a = *(const float4*)(att + (size_t)i * 4);
    lm[0] = fmaxf(lm[0], a.x); lm[1] = fmaxf(lm[1], a.y);
    lm[2] = fmaxf(lm[2], a.z); lm[3] = fmaxf(lm[3], a.w);
  }
#pragma unroll
  for (int h = 0; h < 4; ++h) {
    red[tid] = lm[h]; __syncthreads();
    for (int off = 128; off > 0; off >>= 1) {
      if (tid < off) red[tid] = fmaxf(red[tid], red[tid + off]);
      __syncthreads();
    }
    if (tid == 0) mh[h] = red[0];
    __syncthreads();
  }
  float ls[4] = {0, 0, 0, 0};
  for (int i = s + tid; i < e; i += 256) {
    float4 a = *(const float4*)(att + (size_t)i * 4);
    ls[0] += expf(a.x - mh[0]); ls[1] += expf(a.y - mh[1]);
    ls[2] += expf(a.z - mh[2]); ls[3] += expf(a.w - mh[3]);
  }
#pragma unroll
  for (int h = 0; h < 4; ++h) {
    red[tid] = ls[h]; __syncthreads();
    for (int off = 128; off > 0; off >>= 1) {
      if (tid < off) red[tid] += red[tid + off];
      __syncthreads();
    }
    if (tid == 0) sh[h] = red[0];
    __syncthreads();
  }
  for (int i = s + tid; i < e; i += 256) {
    float4 a = *(const float4*)(att + (size_t)i * 4);
    float4 o;
    o.x = expf(a.x - mh[0]) / sh[0];
    o.y = expf(a.y - mh[1]) / sh[1];
    o.z = expf(a.z - mh[2]) / sh[2];
    o.w = expf(a.w - mh[3]) / sh[3];
    *(float4*)(alpha + (size_t)i * 4) = o;
  }
}

// ---------------- LayerNorms (bf16 in/out) ----------------
__global__ void ln1_k(const unsigned short* __restrict__ mo, const unsigned short* __restrict__ x,
                      const float* __restrict__ g, const float* __restrict__ b,
                      unsigned short* __restrict__ x1) {
  int node = blockIdx.x * 4 + (threadIdx.x >> 6);
  if (node >= NN) return;
  int lane = threadIdx.x & 63;
  int c = lane * 4;
  ushort4 a = *(const ushort4*)(mo + (size_t)node * HIDDEN + c);
  ushort4 xx = *(const ushort4*)(x + (size_t)node * HIDDEN + c);
  float v0 = b2f(a.x) + b2f(xx.x), v1 = b2f(a.y) + b2f(xx.y);
  float v2 = b2f(a.z) + b2f(xx.z), v3 = b2f(a.w) + b2f(xx.w);
  float sm = v0 + v1 + v2 + v3;
#pragma unroll
  for (int off = 1; off < 64; off <<= 1) sm += __shfl_xor(sm, off);
  float mu = sm * (1.f / 256.f);
  float d0 = v0 - mu, d1 = v1 - mu, d2 = v2 - mu, d3 = v3 - mu;
  float sq = d0 * d0 + d1 * d1 + d2 * d2 + d3 * d3;
#pragma unroll
  for (int off = 1; off < 64; off <<= 1) sq += __shfl_xor(sq, off);
  float inv = rsqrtf(sq * (1.f / 256.f) + LN_EPS);
  ushort4 ob;
  ob.x = f2b(g[c + 0] * d0 * inv + b[c + 0]);
  ob.y = f2b(g[c + 1] * d1 * inv + b[c + 1]);
  ob.z = f2b(g[c + 2] * d2 * inv + b[c + 2]);
  ob.w = f2b(g[c + 3] * d3 * inv + b[c + 3]);
  *(ushort4*)(x1 + (size_t)node * HIDDEN + c) = ob;
}

__global__ void ln2_k(const unsigned short* __restrict__ ff2o, const float* __restrict__ ffb2,
                      const unsigned short* __restrict__ x1,
                      const float* __restrict__ g, const float* __restrict__ b,
                      unsigned short* __restrict__ x2) {
  int node = blockIdx.x * 4 + (threadIdx.x >> 6);
  if (node >= NN) return;
  int lane = threadIdx.x & 63;
  int c = lane * 4;
  ushort4 a = *(const ushort4*)(ff2o + (size_t)node * HIDDEN + c);
  ushort4 xx = *(const ushort4*)(x1 + (size_t)node * HIDDEN + c);
  float v0 = b2f(a.x) + ffb2[c + 0] + b2f(xx.x), v1 = b2f(a.y) + ffb2[c + 1] + b2f(xx.y);
  float v2 = b2f(a.z) + ffb2[c + 2] + b2f(xx.z), v3 = b2f(a.w) + ffb2[c + 3] + b2f(xx.w);
  float sm = v0 + v1 + v2 + v3;
#pragma unroll
  for (int off = 1; off < 64; off <<= 1) sm += __shfl_xor(sm, off);
  float mu = sm * (1.f / 256.f);
  float d0 = v0 - mu, d1 = v1 - mu, d2 = v2 - mu, d3 = v3 - mu;
  float sq = d0 * d0 + d1 * d1 + d2 * d2 + d3 * d3;
#pragma unroll
  for (int off = 1; off < 64; off <<= 1) sq += __shfl_xor(sq, off);
  float inv = rsqrtf(sq * (1.f / 256.f) + LN_EPS);
  ushort4 ob;
  ob.x = f2b(g[c + 0] * d0 * inv + b[c + 0]);
  ob.y = f2b(g[c + 1] * d1 * inv + b[c + 1]);
  ob.z = f2b(g[c + 2] * d2 * inv + b[c + 2]);
  ob.w = f2b(g[c + 3] * d3 * inv + b[c + 3]);
  *(ushort4*)(x2 + (size_t)node * HIDDEN + c) = ob;
}

// ---------------- readout (output 0) ----------------
__global__ void readout_k(const unsigned short* __restrict__ x2, const int* __restrict__ start,
                          float* __restrict__ out0) {
  int g = blockIdx.x;
  int c = threadIdx.x;
  float acc = 0.f;
  for (int i = start[g]; i < start[g + 1]; ++i) acc += b2f(x2[(size_t)i * HIDDEN + c]);
  out0[(size_t)g * HIDDEN + c] = acc;
}

// ---------------- workspace layout (bytes) ----------------
#define PADROWSZ 25690112ull   // 50176*256*2
static const size_t OFF_BUFA   = 0;          // h_bf / yv / ff1o,ff2o,x2 (phase-overlapped)
static const size_t OFF_C01    = 128000000;
static const size_t OFF_HG0    = 179200000;                 // padded 50176 rows
static const size_t OFF_HA0    = OFF_HG0 + PADROWSZ;
static const size_t OFF_M1     = OFF_HA0 + PADROWSZ;
static const size_t OFF_F1     = OFF_M1 + PADROWSZ;
static const size_t OFF_XCAT   = OFF_F1 + PADROWSZ;         // 281960448
static const size_t OFF_XB     = OFF_XCAT + 51200000;
static const size_t OFF_MO     = OFF_XB + 25600000;
static const size_t OFF_X1     = OFF_MO + 25600000;
static const size_t OFF_ATT    = OFF_X1 + 25600000;
static const size_t OFF_ALPHA  = OFF_ATT + 800000;
static const size_t OFF_ELR0   = OFF_ALPHA + 800000;
static const size_t OFF_ELR1   = OFF_ELR0 + 1600000;
static const size_t OFF_START  = OFF_ELR1 + 1600000;
static const size_t OFF_DEGO   = OFF_START + 1024;
static const size_t OFF_DEGI   = OFF_DEGO + 200704;
static const size_t OFF_FILL   = OFF_DEGI + 200704;
static const size_t OFF_NS     = OFF_FILL + 200704;
static const size_t OFF_ND     = OFF_NS + 200704;
static const size_t OFF_ROWP   = OFF_ND + 200704;
static const size_t OFF_BSUM   = OFF_ROWP + 200704;
static const size_t OFF_BOFF   = OFF_BSUM + 1024;
static const size_t OFF_CSRS   = OFF_BOFF + 1024;
static const size_t OFF_W01T   = OFF_CSRS + 3200000;
static const size_t OFF_W1T    = OFF_W01T + 1310720;
static const size_t OFF_W1GT   = OFF_W1T + 131072;
static const size_t OFF_GATEWT = OFF_W1GT + 131072;
static const size_t OFF_WMVT   = OFF_GATEWT + 262144;
static const size_t OFF_CTWT   = OFF_WMVT + 1048576;
static const size_t OFF_FFW1T  = OFF_CTWT + 524288;
static const size_t OFF_FFW2T  = OFF_FFW1T + 262144;
static const size_t WS_NEED    = OFF_FFW2T + 262144;

extern "C" void kernel_launch(void* const* d_in, const int* in_sizes, int n_in,
                              void* d_out, int out_size, void* d_ws, size_t ws_size,
                              hipStream_t stream) {
  if (ws_size < WS_NEED) return;

  const float* h       = (const float*)d_in[0];
  const float* gcn_w0  = (const float*)d_in[1];
  const float* gcn_b0  = (const float*)d_in[2];
  const float* gcn_w1  = (const float*)d_in[3];
  const float* gcn_b1  = (const float*)d_in[4];
  const float* bn_gcn0_g = (const float*)d_in[5];
  const float* bn_gcn0_b = (const float*)d_in[6];
  const float* bn_gcn1_g = (const float*)d_in[7];
  const float* bn_gcn1_b = (const float*)d_in[8];
  const float* gat_w0  = (const float*)d_in[9];
  const float* gat_al0 = (const float*)d_in[10];
  const float* gat_ar0 = (const float*)d_in[11];
  const float* gat_bias0 = (const float*)d_in[12];
  const float* gat_w1  = (const float*)d_in[13];
  const float* gat_al1 = (const float*)d_in[14];
  const float* gat_ar1 = (const float*)d_in[15];
  const float* gat_bias1 = (const float*)d_in[16];
  const float* bn_gat0_g = (const float*)d_in[17];
  const float* bn_gat0_b = (const float*)d_in[18];
  const float* bn_gat1_g = (const float*)d_in[19];
  const float* bn_gat1_b = (const float*)d_in[20];
  const float* gate_w  = (const float*)d_in[21];
  const float* gate_b  = (const float*)d_in[22];
  const float* qw      = (const float*)d_in[23];
  const float* kw      = (const float*)d_in[24];
  const float* vw      = (const float*)d_in[25];
  const float* ct_w    = (const float*)d_in[26];
  const float* ff_w1   = (const float*)d_in[27];
  const float* ff_b1   = (const float*)d_in[28];
  const float* ff_w2   = (const float*)d_in[29];
  const float* ff_b2   = (const float*)d_in[30];
  const float* ln_g    = (const float*)d_in[31];
  const float* ln_b    = (const float*)d_in[32];
  const int* srcv = (const int*)d_in[33];
  const int* dstv = (const int*)d_in[34];
  const int* gid  = (const int*)d_in[35];

  char* ws = (char*)d_ws;
  unsigned short* h_bf = (unsigned short*)(ws + OFF_BUFA);
  unsigned short* yv   = (unsigned short*)(ws + OFF_BUFA);
  unsigned short* ff1o = (unsigned short*)(ws + OFF_BUFA);
  unsigned short* ff2o = (unsigned short*)(ws + OFF_BUFA + 51200000);
  unsigned short* x2   = (unsigned short*)(ws + OFF_BUFA + 76800000);
  unsigned short* c01  = (unsigned short*)(ws + OFF_C01);
  unsigned short* hg0  = (unsigned short*)(ws + OFF_HG0);
  unsigned short* ha0  = (unsigned short*)(ws + OFF_HA0);
  unsigned short* m1   = (unsigned short*)(ws + OFF_M1);
  unsigned short* f1   = (unsigned short*)(ws + OFF_F1);
  unsigned short* xcat = (unsigned short*)(ws + OFF_XCAT);
  unsigned short* xb   = (unsigned short*)(ws + OFF_XB);
  unsigned short* mo   = (unsigned short*)(ws + OFF_MO);
  unsigned short* x1   = (unsigned short*)(ws + OFF_X1);
  float* att           = (float*)(ws + OFF_ATT);
  float* alpha         = (float*)(ws + OFF_ALPHA);
  float* elr0          = (float*)(ws + OFF_ELR0);
  float* elr1          = (float*)(ws + OFF_ELR1);
  int* start   = (int*)(ws + OFF_START);
  int* deg_out = (int*)(ws + OFF_DEGO);
  int* deg_in  = (int*)(ws + OFF_DEGI);
  int* fill    = (int*)(ws + OFF_FILL);
  float* ns    = (float*)(ws + OFF_NS);
  float* nd    = (float*)(ws + OFF_ND);
  int* row_ptr = (int*)(ws + OFF_ROWP);
  int* bsum    = (int*)(ws + OFF_BSUM);
  int* boff    = (int*)(ws + OFF_BOFF);
  int* csr_src = (int*)(ws + OFF_CSRS);
  unsigned short* w01t   = (unsigned short*)(ws + OFF_W01T);
  unsigned short* w1t    = (unsigned short*)(ws + OFF_W1T);
  unsigned short* w1gt   = (unsigned short*)(ws + OFF_W1GT);
  unsigned short* gatewt = (unsigned short*)(ws + OFF_GATEWT);
  unsigned short* wmvt   = (unsigned short*)(ws + OFF_WMVT);
  unsigned short* ctwt   = (unsigned short*)(ws + OFF_CTWT);
  unsigned short* ffw1t  = (unsigned short*)(ws + OFF_FFW1T);
  unsigned short* ffw2t  = (unsigned short*)(ws + OFF_FFW2T);

  float* out0 = (float*)d_out;
  float* out1 = out0 + NG * HIDDEN;

  hipMemsetAsync(deg_out, 0, 3 * 200704, stream);  // deg_out, deg_in, fill contiguous
  hipMemsetAsync(out1, 0, NG * DIN * 4, stream);
  hipMemsetAsync(att, 0, NN * 4 * 4, stream);

  // weight prep (one kernel, 9 jobs) + mw
  PrepJobs PJ;
  PJ.j[0] = {gcn_w0, w01t, 1280, 256, 0};
  PJ.j[1] = {gat_w0, w01t + 256 * 1280, 1280, 256, 0};
  PJ.j[2] = {gcn_w1, w1t, 256, 256, 0};
  PJ.j[3] = {gat_w1, w1gt, 256, 256, 0};
  PJ.j[4] = {gate_w, gatewt, 512, 256, 0};
  PJ.j[5] = {ct_w, ctwt, 1024, 256, 0};
  PJ.j[6] = {ff_w1, ffw1t, 256, 512, 0};
  PJ.j[7] = {ff_w2, ffw2t, 512, 256, 0};
  PJ.j[8] = {vw, wmvt + 1024 * 256, 1024, 256, 1};
  prep_k<<<dim3(1280, 9), 256, 0, stream>>>(PJ);
  mw_k<<<1024, 256, 0, stream>>>(qw, kw, wmvt);

  // graph structure
  graph_bounds_k<<<(NN + 255) / 256, 256, 0, stream>>>(gid, start, NN);
  degrees_k<<<(NE + 255) / 256, 256, 0, stream>>>(srcv, dstv, deg_out, deg_in, NE);
  invsqrt_k<<<(NN + 255) / 256, 256, 0, stream>>>(deg_out, deg_in, ns, nd, NN);
  const int NB_SCAN = (NN + 255) / 256;
  scan_local_k<<<NB_SCAN, 256, 0, stream>>>(deg_in, row_ptr, bsum);
  scan_bsum_k<<<1, 256, 0, stream>>>(bsum, boff, NB_SCAN, row_ptr);
  scan_add_k<<<NB_SCAN, 256, 0, stream>>>(row_ptr, boff);
  fill_csr_k<<<(NE + 255) / 256, 256, 0, stream>>>(srcv, dstv, row_ptr, fill, csr_src, NE);

  cvt_avg_k<<<NN / 50, 256, 0, stream>>>(h, gid, h_bf, out1);
  div_avg_k<<<(NG * DIN + 255) / 256, 256, 0, stream>>>(start, out1);

  const int MB2 = (NN + 255) / 256;       // 196
  // GEMM1 + elr0 epilogue on GAT half
  gemm_bf16<6><<<dim3(4, MB2), 256, 0, stream>>>(h_bf, w01t, nullptr, c01, nullptr, NN, 1280, 512,
                                                 nullptr, elr0, nullptr, gat_al0, gat_ar0, 256);
  gcn_agg_k<<<NN / 4, 256, 0, stream>>>(c01, 512, row_ptr, csr_src, ns, nd,
                                        gcn_b0, bn_gcn0_g, bn_gcn0_b, nullptr, 0, hg0, 256);
  gat_agg_k<<<NN / 4, 256, 0, stream>>>(c01 + 256, 512, row_ptr, csr_src, elr0,
                                        gat_bias0, bn_gat0_g, bn_gat0_b, nullptr, 0, ha0, 256);
  // layer 1: stacked [hg0; ha0] @ {w1t|w1gt} -> [m1; f1]; elr1 from GAT rows
  gemm_bf16<7><<<dim3(2, 2 * (NN2 / 256)), 256, 0, stream>>>(hg0, w1t, w1gt, m1, nullptr,
                                                             2 * NN2, 256, 256,
                                                             nullptr, elr1, nullptr,
                                                             gat_al1, gat_ar1, NN2);
  gcn_agg_k<<<NN / 4, 256, 0, stream>>>(m1, 256, row_ptr, csr_src, ns, nd,
                                        gcn_b1, bn_gcn1_g, bn_gcn1_b, hg0, 256, xcat, 512);
  gat_agg_k<<<NN / 4, 256, 0, stream>>>(f1, 256, row_ptr, csr_src, elr1,
                                        gat_bias1, bn_gat1_g, bn_gat1_b, ha0, 256, xcat + 256, 512);
  // gate GEMM with fused sigmoid-combine -> xb
  gemm_bf16<3><<<dim3(2, MB2), 256, 0, stream>>>(xcat, gatewt, nullptr, xb, gate_b, NN, 512, 256,
                                                 xcat, nullptr, nullptr, nullptr, nullptr, 0);
  // transformer: att fused into M-half epilogue; V-half stored
  gemm_bf16<4><<<dim3(16, MB2), 256, 0, stream>>>(xb, wmvt, nullptr, yv, nullptr, NN, 256, 2048,
                                                  xb, att, nullptr, nullptr, nullptr, 0);
  gsoftmax_k<<<NG, 256, 0, stream>>>(att, start, alpha);
  gemm_bf16<5><<<dim3(2, MB2), 256, 0, stream>>>(yv, ctwt, nullptr, mo, nullptr, NN, 1024, 256,
                                                 nullptr, nullptr, alpha, nullptr, nullptr, 0);
  ln1_k<<<NN / 4, 256, 0, stream>>>(mo, xb, ln_g, ln_b, x1);
  gemm_bf16<2><<<dim3(4, MB2), 256, 0, stream>>>(x1, ffw1t, nullptr, ff1o, ff_b1, NN, 256, 512,
                                                 nullptr, nullptr, nullptr, nullptr, nullptr, 0);
  gemm_bf16<0><<<dim3(2, MB2), 256, 0, stream>>>(ff1o, ffw2t, nullptr, ff2o, nullptr, NN, 512, 256,
                                                 nullptr, nullptr, nullptr, nullptr, nullptr, 0);
  ln2_k<<<NN / 4, 256, 0, stream>>>(ff2o, ff_b2, x1, ln_g, ln_b, x2);
  readout_k<<<NG, 256, 0, stream>>>(x2, start, out0);
}